// Round 1
// baseline (367.792 us; speedup 1.0000x reference)
//
#include <hip/hip_runtime.h>
#include <math.h>

#define BB 16
#define CC 64
#define HH 256
#define WW 256
#define HWX (HH * WW)          // 65536 pixels per image per channel
#define NPIX (BB * HWX)        // 1,048,576 total output pixels

// Kernel 1: 1x1 conv (channel contraction) + exp. Each thread computes 4
// consecutive pixels (float4 loads = 16B/lane coalescing sweet spot).
// Writes e0 (exp of channel 0) and s = e0 + e1 (channel sum) to workspace.
__global__ __launch_bounds__(256) void conv_exp_kernel(
    const float* __restrict__ x,
    const float* __restrict__ Wt,     // [2,64]
    const float* __restrict__ bias,   // [2]
    float* __restrict__ e0,
    float* __restrict__ s)
{
    __shared__ float w0[CC];
    __shared__ float w1[CC];
    const int tid = threadIdx.x;
    if (tid < CC) {
        w0[tid] = Wt[tid];        // W[0][c]
        w1[tid] = Wt[CC + tid];   // W[1][c]
    }
    __syncthreads();

    const float b0 = bias[0];
    const float b1 = bias[1];

    const long long p4 = (long long)blockIdx.x * blockDim.x + tid;
    const long long base = p4 * 4;            // first pixel index
    if (base >= NPIX) return;
    const int bimg = (int)(base >> 16);       // / 65536
    const int q    = (int)(base & 65535);     // within-image pixel offset
    const float* xp = x + (long long)bimg * CC * HWX + q;

    float4 a0 = make_float4(b0, b0, b0, b0);
    float4 a1 = make_float4(b1, b1, b1, b1);

    #pragma unroll 8
    for (int c = 0; c < CC; ++c) {
        const float4 v = *(const float4*)(xp + (long long)c * HWX);
        const float wc0 = w0[c];
        const float wc1 = w1[c];
        a0.x = fmaf(v.x, wc0, a0.x);
        a0.y = fmaf(v.y, wc0, a0.y);
        a0.z = fmaf(v.z, wc0, a0.z);
        a0.w = fmaf(v.w, wc0, a0.w);
        a1.x = fmaf(v.x, wc1, a1.x);
        a1.y = fmaf(v.y, wc1, a1.y);
        a1.z = fmaf(v.z, wc1, a1.z);
        a1.w = fmaf(v.w, wc1, a1.w);
    }

    float4 E0, E1, S;
    E0.x = __expf(a0.x); E0.y = __expf(a0.y); E0.z = __expf(a0.z); E0.w = __expf(a0.w);
    E1.x = __expf(a1.x); E1.y = __expf(a1.y); E1.z = __expf(a1.z); E1.w = __expf(a1.w);
    S.x = E0.x + E1.x; S.y = E0.y + E1.y; S.z = E0.z + E1.z; S.w = E0.w + E1.w;

    *(float4*)(e0 + base) = E0;
    *(float4*)(s  + base) = S;
}

// Kernel 2: 3x3 edge-clamped box sum over s, then out = e0 / boxsum.
// s (4 MiB) was just written -> L2 resident; 9 taps are cheap.
__global__ __launch_bounds__(256) void box_div_kernel(
    const float* __restrict__ e0,
    const float* __restrict__ s,
    float* __restrict__ out)
{
    const int idx = blockIdx.x * blockDim.x + threadIdx.x;
    if (idx >= NPIX) return;
    const int bimg = idx >> 16;
    const int q    = idx & 65535;
    const int h = q >> 8;
    const int w = q & 255;

    const int hm = (h > 0)      ? h - 1 : 0;
    const int hp = (h < HH - 1) ? h + 1 : HH - 1;
    const int wm = (w > 0)      ? w - 1 : 0;
    const int wp = (w < WW - 1) ? w + 1 : WW - 1;

    const float* sb = s + bimg * HWX;
    const int rm = hm * WW, r0 = h * WW, rp = hp * WW;

    const float sum =
        sb[rm + wm] + sb[rm + w] + sb[rm + wp] +
        sb[r0 + wm] + sb[r0 + w] + sb[r0 + wp] +
        sb[rp + wm] + sb[rp + w] + sb[rp + wp];

    out[idx] = e0[idx] / sum;
}

extern "C" void kernel_launch(void* const* d_in, const int* in_sizes, int n_in,
                              void* d_out, int out_size, void* d_ws, size_t ws_size,
                              hipStream_t stream) {
    const float* x    = (const float*)d_in[0];
    const float* Wt   = (const float*)d_in[1];
    const float* bias = (const float*)d_in[2];
    float* out = (float*)d_out;

    float* e0 = (float*)d_ws;          // NPIX floats = 4 MiB
    float* s  = e0 + NPIX;             // NPIX floats = 4 MiB

    // Kernel 1: NPIX/4 threads
    {
        const int threads = 256;
        const int total = NPIX / 4;    // 262,144
        const int blocks = (total + threads - 1) / threads;  // 1024
        conv_exp_kernel<<<blocks, threads, 0, stream>>>(x, Wt, bias, e0, s);
    }
    // Kernel 2: NPIX threads
    {
        const int threads = 256;
        const int blocks = (NPIX + threads - 1) / threads;   // 4096
        box_div_kernel<<<blocks, threads, 0, stream>>>(e0, s, out);
    }
}